// Round 1
// baseline (63862.927 us; speedup 1.0000x reference)
//
#include <hip/hip_runtime.h>
#include <cmath>

// Problem constants (match reference)
#define B 32
#define T 512
#define D_IN 512
#define H 1024
#define NG 4096      // 4*H, gate columns (i,f,g,o)
#define L 4
#define D_OUT 512
#define CHUNK 128    // K-split chunk; divides both D_IN(512) and H(1024)

// ---------------------------------------------------------------------------
// Kernel 1: partial gate GEMM.
// gates[32,4096] = A[32,Kx] @ Wx[Kx,4096] + Hprev[32,H] @ Wh[H,4096]
// K-split into CHUNK-sized chunks (blockIdx.y). Each chunk lies entirely in
// the x-part or h-part because CHUNK | Kx and CHUNK | H.
// Block: 256 threads = 4 waves. Wave bg handles batch rows bg*8..bg*8+7.
// Lane jj (0..63) handles hidden col jb*64+jj across all 4 gates.
// Each weight element is read exactly once per dispatch (reused across 8
// batch rows in registers); A-chunk is staged in LDS, read via wave-uniform
// broadcasts (conflict-free).
// ---------------------------------------------------------------------------
__global__ __launch_bounds__(256) void gates_partial(
    const float* __restrict__ Ax, int sx, int Kx,   // input rows [B,Kx], row stride sx
    const float* __restrict__ Hprev,                // [B,H]
    const float* __restrict__ Wx,                   // [Kx,4096]
    const float* __restrict__ Wh,                   // [H,4096]
    float* __restrict__ part)                       // [nparts][B][4096]
{
    __shared__ float a_sh[B * CHUNK];               // 16 KiB

    const int jb = blockIdx.x;                      // 0..15 (64 hidden cols each)
    const int kc = blockIdx.y;                      // chunk id
    const int k0 = kc * CHUNK;

    const float* A; int astr; int acol0;
    const float* W; int wrow0;
    if (k0 < Kx) { A = Ax;    astr = sx; acol0 = k0;      W = Wx; wrow0 = k0; }
    else         { A = Hprev; astr = H;  acol0 = k0 - Kx; W = Wh; wrow0 = k0 - Kx; }

    // Stage A chunk: a_sh[b*CHUNK + kk]. Global reads coalesced along kk;
    // LDS writes consecutive -> conflict-free.
    for (int idx = threadIdx.x; idx < B * CHUNK; idx += 256) {
        int b  = idx >> 7;            // CHUNK == 128
        int kk = idx & (CHUNK - 1);
        a_sh[idx] = A[(size_t)b * astr + acol0 + kk];
    }
    __syncthreads();

    const int jj = threadIdx.x & 63;
    const int bg = threadIdx.x >> 6;                // wave id, uniform per wave
    const float* wp = W + (size_t)wrow0 * NG + jb * 64 + jj;

    float acc[4][8];
    #pragma unroll
    for (int g = 0; g < 4; ++g)
        #pragma unroll
        for (int r = 0; r < 8; ++r) acc[g][r] = 0.f;

    const float* ash = &a_sh[(bg * 8) * CHUNK];

    #pragma unroll 4
    for (int kk = 0; kk < CHUNK; ++kk) {
        // 4 coalesced weight loads (one per gate), each used for 8 batch rows
        float w0 = wp[(size_t)kk * NG];
        float w1 = wp[(size_t)kk * NG + H];
        float w2 = wp[(size_t)kk * NG + 2 * H];
        float w3 = wp[(size_t)kk * NG + 3 * H];
        #pragma unroll
        for (int r = 0; r < 8; ++r) {
            float a = ash[r * CHUNK + kk];          // wave-uniform broadcast
            acc[0][r] += a * w0;
            acc[1][r] += a * w1;
            acc[2][r] += a * w2;
            acc[3][r] += a * w3;
        }
    }

    float* pp = part + (size_t)kc * B * NG + jb * 64 + jj;
    #pragma unroll
    for (int g = 0; g < 4; ++g)
        #pragma unroll
        for (int r = 0; r < 8; ++r)
            pp[(size_t)(bg * 8 + r) * NG + g * H] = acc[g][r];
}

// ---------------------------------------------------------------------------
// Kernel 2: reduce K-split partials + bias, apply LSTM cell update.
// One thread per (b, j) hidden unit; reads its 4 gate columns.
// ---------------------------------------------------------------------------
__global__ __launch_bounds__(256) void cell_update(
    const float* __restrict__ part, int nparts,
    const float* __restrict__ bias,                 // [4096]
    float* __restrict__ c,                          // [B*H]
    float* __restrict__ h)                          // [B*H]
{
    int idx = blockIdx.x * 256 + threadIdx.x;       // 0..32767
    int b = idx >> 10;
    int j = idx & (H - 1);

    float s[4];
    #pragma unroll
    for (int g = 0; g < 4; ++g) s[g] = bias[g * H + j];

    for (int p = 0; p < nparts; ++p) {
        const float* pp = part + ((size_t)p * B + b) * NG + j;
        #pragma unroll
        for (int g = 0; g < 4; ++g) s[g] += pp[g * H];
    }

    float ig = 1.f / (1.f + expf(-s[0]));
    float fg = 1.f / (1.f + expf(-s[1]));
    float gg = tanhf(s[2]);
    float og = 1.f / (1.f + expf(-s[3]));
    float cn = fg * c[idx] + ig * gg;
    c[idx] = cn;
    h[idx] = og * tanhf(cn);
}

// ---------------------------------------------------------------------------
// Kernel 3: output projection out[B,D_OUT] = h @ Wout + bout (one-off)
// ---------------------------------------------------------------------------
__global__ __launch_bounds__(256) void out_proj(
    const float* __restrict__ h,                    // [B,H]
    const float* __restrict__ Wout,                 // [H,D_OUT]
    const float* __restrict__ bout,                 // [D_OUT]
    float* __restrict__ out)                        // [B,D_OUT]
{
    int idx = blockIdx.x * 256 + threadIdx.x;       // 0..16383
    int b = idx >> 9;
    int o = idx & (D_OUT - 1);
    float s = bout[o];
    for (int j = 0; j < H; ++j)
        s += h[(size_t)b * H + j] * Wout[(size_t)j * D_OUT + o];
    out[idx] = s;
}

extern "C" void kernel_launch(void* const* d_in, const int* in_sizes, int n_in,
                              void* d_out, int out_size, void* d_ws, size_t ws_size,
                              hipStream_t stream) {
    const float* x    = (const float*)d_in[0];   // [B,T,D_IN]
    const float* Wx0  = (const float*)d_in[1];   // [D_IN,4H]
    const float* Wh0  = (const float*)d_in[2];   // [H,4H]
    const float* b0   = (const float*)d_in[3];   // [4H]
    const float* Wx   = (const float*)d_in[4];   // [L-1,H,4H]
    const float* Wh   = (const float*)d_in[5];   // [L-1,H,4H]
    const float* bb   = (const float*)d_in[6];   // [L-1,4H]
    const float* Wout = (const float*)d_in[7];   // [H,D_OUT]
    const float* bout = (const float*)d_in[8];   // [D_OUT]
    float* out = (float*)d_out;

    // Workspace layout (≈9 MiB): h[L][B*H], c[L][B*H], part[16][B][4096]
    float* hbuf = (float*)d_ws;
    float* cbuf = hbuf + (size_t)L * B * H;
    float* part = cbuf + (size_t)L * B * H;

    // Zero initial h and c (ws is poisoned with 0xAA before every call)
    hipMemsetAsync(hbuf, 0, (size_t)2 * L * B * H * sizeof(float), stream);

    for (int t = 0; t < T; ++t) {
        for (int l = 0; l < L; ++l) {
            const float* Ax; int sx; int Kx;
            const float* wx; const float* wh; const float* bias;
            if (l == 0) {
                Ax = x + (size_t)t * D_IN; sx = T * D_IN; Kx = D_IN;
                wx = Wx0; wh = Wh0; bias = b0;
            } else {
                Ax = hbuf + (size_t)(l - 1) * B * H; sx = H; Kx = H;
                wx = Wx + (size_t)(l - 1) * H * NG;
                wh = Wh + (size_t)(l - 1) * H * NG;
                bias = bb + (size_t)(l - 1) * NG;
            }
            int nparts = (Kx + H) / CHUNK;          // 12 for layer 0, 16 otherwise
            gates_partial<<<dim3(16, nparts), 256, 0, stream>>>(
                Ax, sx, Kx, hbuf + (size_t)l * B * H, wx, wh, part);
            cell_update<<<dim3(B * H / 256), 256, 0, stream>>>(
                part, nparts, bias, cbuf + (size_t)l * B * H, hbuf + (size_t)l * B * H);
        }
    }
    out_proj<<<dim3(B * D_OUT / 256), 256, 0, stream>>>(
        hbuf + (size_t)(L - 1) * B * H, Wout, bout, out);
}